// Round 6
// baseline (265.232 us; speedup 1.0000x reference)
//
#include <hip/hip_runtime.h>
#include <stdint.h>

typedef unsigned short u16;

#define MTOK 4096
#define CIN  3072
#define COUT 3072
#define RANK 32
#define KT48 48
#define RS   3136       // row stride for xdq/xs_bf/wdq (6272 B: gcd(6272,4096)=128 -> good HBM channel spread)
#define LKSPLIT 16
#define LKC (CIN/LKSPLIT)   // 192 = 3 k-tiles of 64

// quant grid: [0, QBLK) activation quant rows-parts, [QBLK, QBLK+PDT_BLK) pd transpose
#define QBLK (MTOK*3)       // 12288
#define PDT_BLK 24
// lora_wdq grid: [0, LORA_BLK) lora panels, rest wdq rows
#define LORA_BLK (MTOK/128*LKSPLIT)  // 512
#define WDQ_BLK COUT                 // 3072

// Workspace:
//   xdq:     (MTOK, RS) bf16    quantized activations (cols 0..3071 valid)
//   wdq:     (COUT, RS) bf16    dequantized weights
//   xs_bf:   (MTOK, RS) bf16    smoothed activations (bf16 copy for lora GEMM)
//   pdT_bf:  (RANK, CIN) bf16   proj_down transposed
//   pu_bf:   (COUT, RANK) bf16  proj_up cast
//   lora_bf: (MTOK, RANK) bf16  reduced lora activations
//   lp:      (LKSPLIT, MTOK, RANK) f32  lora K-split partials (deterministic)

typedef __attribute__((ext_vector_type(8))) short bf16x8;
typedef __attribute__((ext_vector_type(4))) float f32x4;

__device__ __forceinline__ u16 f2bf(float f) {
  union { float f; unsigned u; } v; v.f = f;
  unsigned r = v.u + 0x7FFFu + ((v.u >> 16) & 1u);  // RNE
  return (u16)(r >> 16);
}

__device__ __forceinline__ void gload_lds16(const void* g, void* l) {
  __builtin_amdgcn_global_load_lds(
      (const __attribute__((address_space(1))) unsigned int*)g,
      (__attribute__((address_space(3))) unsigned int*)l, 16, 0, 0);
}

__device__ __forceinline__ float quant1(float xs, float ascale, float qd) {
  float q = rintf(xs / qd);                      // jnp.round = RNE, exact IEEE div
  q = fminf(fmaxf(q, -8.f), 7.f);
  return q * ascale;
}

// Kernel 1: streaming quant (writes xdq + xs_bf) + pd transpose blocks.
__global__ __launch_bounds__(256) void quant_kernel(
    const float* __restrict__ x, const float* __restrict__ smooth,
    const float* __restrict__ pd,
    u16* __restrict__ xdq, u16* __restrict__ xs_bf, u16* __restrict__ pdT_bf)
{
  const int b = blockIdx.x;
  const int t = threadIdx.x;
  if (b < QBLK) {
    const int m = b / 3;
    const int part = b - m * 3;
    const int c0 = part * 1024 + t * 4;
    const float4 xv = *(const float4*)(x + (size_t)m * CIN + c0);
    const float4 sv = *(const float4*)(smooth + c0);
    const float xs0 = xv.x / sv.x, xs1 = xv.y / sv.y;
    const float xs2 = xv.z / sv.z, xs3 = xv.w / sv.w;
    // bf16 smoothed copy for the lora GEMM
    ushort4 osb;
    osb.x = f2bf(xs0); osb.y = f2bf(xs1); osb.z = f2bf(xs2); osb.w = f2bf(xs3);
    *(ushort4*)(xs_bf + (size_t)m * RS + c0) = osb;
    // per-64-group quant: 16 lanes x 4 elems = one group
    float a = fmaxf(fmaxf(fabsf(xs0), fabsf(xs1)), fmaxf(fabsf(xs2), fabsf(xs3)));
#pragma unroll
    for (int off = 1; off < 16; off <<= 1) a = fmaxf(a, __shfl_xor(a, off));
    const float ascale = a / 7.0f;
    const float qd = fmaxf(ascale, 1e-8f);
    ushort4 oq;
    oq.x = f2bf(quant1(xs0, ascale, qd));
    oq.y = f2bf(quant1(xs1, ascale, qd));
    oq.z = f2bf(quant1(xs2, ascale, qd));
    oq.w = f2bf(quant1(xs3, ascale, qd));
    *(ushort4*)(xdq + (size_t)m * RS + c0) = oq;
  } else {
    // ---- pd transpose: pdT_bf[r][k] = bf16(pd[k][r]), 128 k per block ----
    const int k0 = (b - QBLK) * 128;
    const int k = k0 + (t >> 3);         // 32 k per wave pass... t>>3 in 0..31
    const int r4 = (t & 7) * 4;
#pragma unroll
    for (int kp = 0; kp < 4; ++kp) {     // cover 128 k: 32 per pass
      const int kk = k + kp * 32;
      const float4 pv = *(const float4*)(pd + (size_t)kk * RANK + r4);
      pdT_bf[(size_t)(r4 + 0) * CIN + kk] = f2bf(pv.x);
      pdT_bf[(size_t)(r4 + 1) * CIN + kk] = f2bf(pv.y);
      pdT_bf[(size_t)(r4 + 2) * CIN + kk] = f2bf(pv.z);
      pdT_bf[(size_t)(r4 + 3) * CIN + kk] = f2bf(pv.w);
    }
  }
}

// Kernel 2: lora panels (pure m97-pattern mini-GEMM from xs_bf / pdT_bf) + wdq rows.
__global__ __launch_bounds__(256) void lora_wdq_kernel(
    const u16* __restrict__ xs_bf, const u16* __restrict__ pdT_bf,
    const int* __restrict__ qw, const float* __restrict__ wsc,
    const float* __restrict__ pu,
    u16* __restrict__ wdq, u16* __restrict__ pu_bf, float* __restrict__ lp)
{
  const int b = blockIdx.x;
  const int t = threadIdx.x;

  if (b < LORA_BLK) {
    __shared__ __align__(16) u16 sA[128 * 64];
    __shared__ __align__(16) u16 sB[32 * 64];
    const int m0 = (b >> 4) * 128;        // 32 m-panels
    const int kblk = b & 15;              // 16 K-splits
    const int wave = t >> 6, lane = t & 63;
    const int lm = lane & 15, q4 = lane >> 4;
    const int xs7 = lm & 7;
    const int lrow = lane >> 3;
    const int gcol = ((lane & 7) ^ lrow) * 8;   // XOR swizzle (same as main gemm)

    f32x4 acc[2][2];
    const f32x4 fz = {0.f, 0.f, 0.f, 0.f};
#pragma unroll
    for (int i = 0; i < 2; ++i)
#pragma unroll
      for (int j = 0; j < 2; ++j) acc[i][j] = fz;

    for (int kt = 0; kt < LKC / 64; ++kt) {
      const int k0 = kblk * LKC + kt * 64;
      // stage A: 128x64 bf16 via async 16B direct-to-LDS
#pragma unroll
      for (int r = 0; r < 4; ++r) {
        const int ci = wave * 4 + r;
        const int row = ci * 8 + lrow;
        gload_lds16(xs_bf + (size_t)(m0 + row) * RS + k0 + gcol,
                    &sA[ci * 512 + lane * 8]);
      }
      // stage B: 32x64 bf16, one chunk per wave
      {
        const int row = wave * 8 + lrow;
        gload_lds16(pdT_bf + (size_t)row * CIN + k0 + gcol,
                    &sB[wave * 512 + lane * 8]);
      }
      __syncthreads();
#pragma unroll
      for (int kk = 0; kk < 2; ++kk) {
        const int csw = ((kk * 4 + q4) ^ xs7) * 8;
        bf16x8 af[2], bfr[2];
#pragma unroll
        for (int i = 0; i < 2; ++i)
          af[i] = *(const bf16x8*)&sA[(wave * 32 + i * 16 + lm) * 64 + csw];
#pragma unroll
        for (int j = 0; j < 2; ++j)
          bfr[j] = *(const bf16x8*)&sB[(j * 16 + lm) * 64 + csw];
#pragma unroll
        for (int i = 0; i < 2; ++i)
#pragma unroll
          for (int j = 0; j < 2; ++j)
            acc[i][j] = __builtin_amdgcn_mfma_f32_16x16x32_bf16(af[i], bfr[j], acc[i][j], 0, 0, 0);
      }
      __syncthreads();
    }
    float* lpk = lp + (size_t)kblk * MTOK * RANK;
#pragma unroll
    for (int i = 0; i < 2; ++i)
#pragma unroll
      for (int j = 0; j < 2; ++j) {
        const int col = j * 16 + lm;
        const int row0 = m0 + wave * 32 + i * 16 + q4 * 4;
#pragma unroll
        for (int r = 0; r < 4; ++r)
          lpk[(size_t)(row0 + r) * RANK + col] = acc[i][j][r];
      }
  } else {
    // ---- weight dequant row + pu_bf cast ----
    const int o = b - LORA_BLK;
    const int4* qrow = (const int4*)(qw + (size_t)o * CIN);
    u16* orow = wdq + (size_t)o * RS;
#pragma unroll
    for (int p = 0; p < 3; ++p) {
      const int c4 = p * 256 + t;
      const int g = (c4 * 4) >> 6;
      const float ws = wsc[g * COUT + o];    // wscales is (G, C_out)
      const int4 qv = qrow[c4];
      ushort4 ov;
      ov.x = f2bf((float)(qv.x - 8) * ws);
      ov.y = f2bf((float)(qv.y - 8) * ws);
      ov.z = f2bf((float)(qv.z - 8) * ws);
      ov.w = f2bf((float)(qv.w - 8) * ws);
      ((ushort4*)orow)[c4] = ov;
    }
    if (t < RANK) pu_bf[(size_t)o * RANK + t] = f2bf(pu[(size_t)o * RANK + t]);
  }
}

// Kernel 3: reduce lora K-split partials -> bf16 lora_bf (M, 32).
__global__ __launch_bounds__(256) void lora_fix_kernel(
    const float* __restrict__ lp, u16* __restrict__ lora_bf)
{
  const int idx = blockIdx.x * 256 + threadIdx.x;   // MTOK*RANK
  const int m = idx >> 5, c = idx & 31;
  float s = 0.f;
#pragma unroll
  for (int k = 0; k < LKSPLIT; ++k) s += lp[((size_t)k * MTOK + m) * RANK + c];
  lora_bf[(size_t)m * RANK + c] = f2bf(s);
}

// Kernel 4: main GEMM 128x128 bf16 MFMA, K=3072, XOR-swizzled LDS, lora-MFMA + bias epilogue.
__global__ __launch_bounds__(256) void gemm_kernel(
    const u16* __restrict__ xdq, const u16* __restrict__ wdq,
    const u16* __restrict__ pu_bf, const u16* __restrict__ lora_bf,
    const float* __restrict__ bias, float* __restrict__ out)
{
  __shared__ __align__(16) u16 sA[128 * 64];
  __shared__ __align__(16) u16 sB[128 * 64];
  const int t = threadIdx.x;
  const int wave = t >> 6, lane = t & 63;
  const int wm = wave >> 1, wn = wave & 1;           // 2x2 wave grid, 64x64 each
  const int m0 = blockIdx.y * 128, n0 = blockIdx.x * 128;
  const int lrow = lane >> 3;
  const int gcol = ((lane & 7) ^ lrow) * 8;          // swizzled global col block

  f32x4 acc[4][4];
  const f32x4 fz = {0.f, 0.f, 0.f, 0.f};
#pragma unroll
  for (int i = 0; i < 4; ++i)
#pragma unroll
    for (int j = 0; j < 4; ++j) acc[i][j] = fz;

  const int lm = lane & 15;
  const int xs7 = lm & 7;
  const int q4 = lane >> 4;

  for (int kt = 0; kt < KT48; ++kt) {
    const u16* Ab = xdq + (size_t)m0 * RS + kt * 64;
    const u16* Bb = wdq + (size_t)n0 * RS + kt * 64;
#pragma unroll
    for (int r = 0; r < 4; ++r) {
      const int ci = wave * 4 + r;
      const int row = ci * 8 + lrow;
      gload_lds16(Ab + (size_t)row * RS + gcol, &sA[ci * 512 + lane * 8]);
      gload_lds16(Bb + (size_t)row * RS + gcol, &sB[ci * 512 + lane * 8]);
    }
    __syncthreads();
#pragma unroll
    for (int kk = 0; kk < 2; ++kk) {
      const int csw = ((kk * 4 + q4) ^ xs7) * 8;
      bf16x8 af[4], bfr[4];
#pragma unroll
      for (int i = 0; i < 4; ++i)
        af[i] = *(const bf16x8*)&sA[(wm * 64 + i * 16 + lm) * 64 + csw];
#pragma unroll
      for (int j = 0; j < 4; ++j)
        bfr[j] = *(const bf16x8*)&sB[(wn * 64 + j * 16 + lm) * 64 + csw];
#pragma unroll
      for (int i = 0; i < 4; ++i)
#pragma unroll
        for (int j = 0; j < 4; ++j)
          acc[i][j] = __builtin_amdgcn_mfma_f32_16x16x32_bf16(af[i], bfr[j], acc[i][j], 0, 0, 0);
    }
    __syncthreads();
  }

  // lora epilogue: acc += lora_act(128x32) . proj_up(128x32)^T (bf16, L2-hot)
  bf16x8 afl[4], bfl[4];
#pragma unroll
  for (int i = 0; i < 4; ++i) {
    const int arow = m0 + wm * 64 + i * 16 + lm;
    afl[i] = *(const bf16x8*)(lora_bf + (size_t)arow * RANK + q4 * 8);
  }
#pragma unroll
  for (int j = 0; j < 4; ++j) {
    const int bcol = n0 + wn * 64 + j * 16 + lm;
    bfl[j] = *(const bf16x8*)(pu_bf + (size_t)bcol * RANK + q4 * 8);
  }
#pragma unroll
  for (int i = 0; i < 4; ++i)
#pragma unroll
    for (int j = 0; j < 4; ++j)
      acc[i][j] = __builtin_amdgcn_mfma_f32_16x16x32_bf16(afl[i], bfl[j], acc[i][j], 0, 0, 0);

  // store: C/D layout col=lane&15, row=(lane>>4)*4+reg  [m89-verified]
#pragma unroll
  for (int j = 0; j < 4; ++j) {
    const int col = n0 + wn * 64 + j * 16 + lm;
    const float bv = bias[col];
#pragma unroll
    for (int i = 0; i < 4; ++i) {
      const int row0 = m0 + wm * 64 + i * 16 + q4 * 4;
#pragma unroll
      for (int r = 0; r < 4; ++r)
        out[(size_t)(row0 + r) * COUT + col] = acc[i][j][r] + bv;
    }
  }
}

extern "C" void kernel_launch(void* const* d_in, const int* in_sizes, int n_in,
                              void* d_out, int out_size, void* d_ws, size_t ws_size,
                              hipStream_t stream) {
  const float* x      = (const float*)d_in[0];
  const int*   qw     = (const int*)d_in[1];
  const float* wsc    = (const float*)d_in[2];
  const float* smooth = (const float*)d_in[3];
  const float* pd     = (const float*)d_in[4];
  const float* pu     = (const float*)d_in[5];
  const float* bias   = (const float*)d_in[6];
  float* out = (float*)d_out;

  u16* xdq     = (u16*)d_ws;                               // 4096*3136*2 = 25.7 MB
  u16* wdq     = xdq + (size_t)MTOK * RS;                  // 3072*3136*2 = 19.3 MB
  u16* xs_bf   = wdq + (size_t)COUT * RS;                  // 4096*3136*2 = 25.7 MB
  u16* pdT_bf  = xs_bf + (size_t)MTOK * RS;                // 32*3072*2   = 0.2 MB
  u16* pu_bf   = pdT_bf + (size_t)RANK * CIN;              // 3072*32*2   = 0.2 MB
  u16* lora_bf = pu_bf + (size_t)COUT * RANK;              // 4096*32*2   = 0.3 MB
  float* lp    = (float*)(lora_bf + (size_t)MTOK * RANK);  // 16*4096*32*4 = 8.4 MB

  quant_kernel<<<QBLK + PDT_BLK, 256, 0, stream>>>(x, smooth, pd, xdq, xs_bf, pdT_bf);
  lora_wdq_kernel<<<LORA_BLK + WDQ_BLK, 256, 0, stream>>>(
      xs_bf, pdT_bf, qw, wsc, pu, wdq, pu_bf, lp);
  lora_fix_kernel<<<MTOK * RANK / 256, 256, 0, stream>>>(lp, lora_bf);
  gemm_kernel<<<dim3(COUT / 128, MTOK / 128), 256, 0, stream>>>(
      xdq, wdq, pu_bf, lora_bf, bias, out);
}